// Round 12
// baseline (882.080 us; speedup 1.0000x reference)
//
#include <hip/hip_runtime.h>
#include <hip/hip_fp16.h>

#define SEQ   64
#define HID   128
#define TOUT  24

typedef unsigned int u32;
typedef _Float16 f16;
typedef __attribute__((ext_vector_type(8))) f16 f16x8;
typedef __attribute__((ext_vector_type(4))) float f32x4;
#define MFMA __builtin_amdgcn_mfma_f32_16x16x32_f16

static __device__ __forceinline__ float sigm(float x){
  return __builtin_amdgcn_rcpf(1.f + __expf(-x));
}
static __device__ __forceinline__ float tanh_fast(float x){
  return fmaf(2.f, __builtin_amdgcn_rcpf(1.f + __expf(-2.f*x)), -1.f);
}

// ---------------- weight prep: fp32 -> MFMA B-fragment fp16 layouts (unchanged) ----
__global__ void prep_kernel(
    const float* __restrict__ eWih0,  const float* __restrict__ eWhh0,
    const float* __restrict__ eWih12, const float* __restrict__ eWhh12,
    const float* __restrict__ aW,
    const float* __restrict__ dWih0,  const float* __restrict__ dWhh0,
    const float* __restrict__ dWih12, const float* __restrict__ dWhh12,
    const float* __restrict__ oW,
    __half* __restrict__ wE0, __half* __restrict__ wE1, __half* __restrict__ wE2,
    __half* __restrict__ wD0, __half* __restrict__ wD1, __half* __restrict__ wD2,
    __half* __restrict__ wAh, __half* __restrict__ wAeF, float* __restrict__ wOT,
    float* __restrict__ dW2)
{
  int id = blockIdx.x*blockDim.x + threadIdx.x;
  if (id < 65536){                                   // wE0: K=128 (Whh only), KT=4
    int m=id, jj=m&7, l=(m>>3)&63, kt=(m>>9)&3, nt=m>>11;
    int col = nt*16 + (l&15), k = kt*32 + ((l>>4)<<3) + jj;
    wE0[m] = __float2half(eWhh0[col*128 + k]); return;
  }
  id -= 65536;
  if (id < 5*131072){                                // wE1,wE2,wD0,wD1,wD2: K=256, KT=8
    int seg = id >> 17, m = id & 131071;
    int jj=m&7, l=(m>>3)&63, kt=(m>>9)&7, nt=m>>12;
    int col = nt*16 + (l&15), k = kt*32 + ((l>>4)<<3) + jj;
    float v;
    if (seg==0)      v = (k<128)? eWih12[col*128+k]         : eWhh12[col*128 + (k-128)];
    else if (seg==1) v = (k<128)? eWih12[65536+col*128+k]   : eWhh12[65536 + col*128 + (k-128)];
    else if (seg==2) v = (k<128)? dWih0[col*130 + 2 + k]    : dWhh0[col*128 + (k-128)];
    else if (seg==3) v = (k<128)? dWih12[col*128+k]         : dWhh12[col*128 + (k-128)];
    else             v = (k<128)? dWih12[65536+col*128+k]   : dWhh12[65536 + col*128 + (k-128)];
    __half* dst = (seg==0)?wE1:(seg==1)?wE2:(seg==2)?wD0:(seg==3)?wD1:wD2;
    dst[m] = __float2half(v); return;
  }
  id -= 5*131072;
  if (id < 16384){                                   // wAh: attn_W[:, :H], KT=4, NT=8
    int m=id, jj=m&7, l=(m>>3)&63, kt=(m>>9)&3, nt=m>>11;
    int col = nt*16 + (l&15), k = kt*32 + ((l>>4)<<3) + jj;
    wAh[m] = __float2half(aW[col*256 + k]); return;
  }
  id -= 16384;
  if (id < 16384){                                   // wAeF: attn_W[:, H:], B-frags
    int m=id, jj=m&7, l=(m>>3)&63, kt=(m>>9)&3, nt=m>>11;
    int col = nt*16 + (l&15), k = kt*32 + ((l>>4)<<3) + jj;
    wAeF[m] = __float2half(aW[col*256 + 128 + k]); return;
  }
  id -= 16384;
  if (id < 512){ int k=id>>1, jo=id&1; wOT[id] = oW[jo*256 + k]; return; }   // [k][2] f32
  id -= 512;
  if (id < 1024){ int col=id>>1, ki=id&1; dW2[id] = dWih0[col*130 + ki]; return; } // [n][2]
}

// ---------------- encoder: 64 blocks x 512 thr, M=16 batch rows (byte-identical) ----
__global__ __launch_bounds__(512) __attribute__((amdgpu_waves_per_eu(2, 2)))
void enc_kernel(
    const float* __restrict__ x, const float* __restrict__ eb0,
    const float* __restrict__ eb12, const float* __restrict__ eWih0,
    const __half* __restrict__ wE0, const __half* __restrict__ wE1,
    const __half* __restrict__ wE2,
    __half* __restrict__ hs0, __half* __restrict__ hs1,
    __half* __restrict__ carryH, float* __restrict__ carryC)
{
  __shared__ __align__(16) __half hT[2][2048];

  const int tid = threadIdx.x, w = tid>>6, lane = tid&63;
  const int l15 = lane&15, g4 = lane>>4;
  const int j = w*16 + l15;
  const int b16 = blockIdx.x*16;
  const int K0 = ((j>>5)*64 + ((j>>3)&3)*16)*8 + (j&7);

  __half* hs0b = hs0 + (size_t)blockIdx.x*131072;
  __half* hs1b = hs1 + (size_t)blockIdx.x*131072;

  for (int layer=0; layer<3; ++layer){
    const __half* W  = (layer==0)? wE0 : (layer==1)? wE1 : wE2;
    const float* bs  = (layer==0)? eb0 : (layer==1)? eb12 : (eb12+512);
    const __half* hinb  = (layer==1)? hs0b : hs1b;     // valid for layer>0
    __half* houtb = (layer==0)? hs0b : (layer==1)? hs1b : nullptr;

    float bias[4];
#pragma unroll
    for (int g=0; g<4; ++g) bias[g] = bs[g*128 + j];
    float2 wx[4];
    if (layer==0){
#pragma unroll
      for (int g=0; g<4; ++g) wx[g] = *(const float2*)(eWih0 + (g*128+j)*2);
    }
    const f16x8* wb = (const f16x8*)W + lane;
    f16x8 Wh[16];                                    // resident W_hh slice
    if (layer==0){
#pragma unroll
      for (int g=0; g<4; ++g)
#pragma unroll
        for (int kt=0; kt<4; ++kt) Wh[g*4+kt] = wb[(size_t)((g*8+w)*4 + kt)*64];
    } else {
#pragma unroll
      for (int g=0; g<4; ++g)
#pragma unroll
        for (int kt=0; kt<4; ++kt) Wh[g*4+kt] = wb[(size_t)((g*8+w)*8 + 4 + kt)*64];
    }
    float c[4] = {0.f,0.f,0.f,0.f};
    ((u32*)hT[0])[tid] = 0u; ((u32*)hT[0])[tid+512] = 0u;
    __syncthreads();

    float2 xv[4]; f16x8 alo[4];
    if (layer==0){
#pragma unroll
      for (int q=0; q<4; ++q) xv[q] = *(const float2*)(x + ((size_t)(b16+g4*4+q)*SEQ + 0)*2);
    } else {
#pragma unroll
      for (int kt=0; kt<4; ++kt) alo[kt] = *(const f16x8*)(hinb + (kt*64+lane)*8);
    }

    int cur = 0;
    for (int t=0; t<SEQ; ++t){
      f16x8 wi[16];
      if (layer>0){                                  // stream W_ih slice (L2)
#pragma unroll
        for (int g=0; g<4; ++g)
#pragma unroll
          for (int kt=0; kt<4; ++kt) wi[g*4+kt] = wb[(size_t)((g*8+w)*8 + kt)*64];
      }
      f16x8 ah[4];
#pragma unroll
      for (int kt=0; kt<4; ++kt) ah[kt] = *(const f16x8*)(hT[cur] + (kt*64+lane)*8);
      float2 xcur[4]; f16x8 acur[4];
      if (layer==0){
#pragma unroll
        for (int q=0; q<4; ++q) xcur[q] = xv[q];
        if (t+1 < SEQ)
#pragma unroll
          for (int q=0; q<4; ++q) xv[q] = *(const float2*)(x + ((size_t)(b16+g4*4+q)*SEQ + t+1)*2);
      } else {
#pragma unroll
        for (int kt=0; kt<4; ++kt) acur[kt] = alo[kt];
        if (t+1 < SEQ)
#pragma unroll
          for (int kt=0; kt<4; ++kt) alo[kt] = *(const f16x8*)(hinb + (size_t)(t+1)*2048 + (kt*64+lane)*8);
      }
      f32x4 acc[4];
#pragma unroll
      for (int g=0; g<4; ++g) acc[g] = (f32x4){0.f,0.f,0.f,0.f};
#pragma unroll
      for (int g=0; g<4; ++g)
#pragma unroll
        for (int kt=0; kt<4; ++kt) acc[g] = MFMA(ah[kt], Wh[g*4+kt], acc[g], 0,0,0);
      if (layer>0){
#pragma unroll
        for (int g=0; g<4; ++g)
#pragma unroll
          for (int kt=0; kt<4; ++kt) acc[g] = MFMA(acur[kt], wi[g*4+kt], acc[g], 0,0,0);
      }
      // pointwise (all 16 rows)
#pragma unroll
      for (int q=0; q<4; ++q){
        float gi = acc[0][q]+bias[0], gf = acc[1][q]+bias[1],
              gg = acc[2][q]+bias[2], go = acc[3][q]+bias[3];
        if (layer==0){
          gi += xcur[q].x*wx[0].x + xcur[q].y*wx[0].y;
          gf += xcur[q].x*wx[1].x + xcur[q].y*wx[1].y;
          gg += xcur[q].x*wx[2].x + xcur[q].y*wx[2].y;
          go += xcur[q].x*wx[3].x + xcur[q].y*wx[3].y;
        }
        float cn = fmaf(sigm(gf), c[q], sigm(gi)*tanh_fast(gg));
        float hn = sigm(go)*tanh_fast(cn);
        c[q] = cn;
        __half hh = __float2half(hn);
        hT[cur^1][K0 + (g4*4+q)*8] = hh;
        if (layer < 2){
          houtb[(size_t)t*2048 + K0 + (g4*4+q)*8] = hh;
        } else {
          // encA overlay on hs0b: [d_local=g4][r4=q][sb=t>>4][ktA=j>>5][laneA][u]
          int off = g4*32768 + q*8192 + (t>>4)*2048 + (j>>5)*512
                  + ((t&15) + ((j>>3)&3)*16)*8 + (j&7);
          hs0b[off] = hh;
        }
        if (t == SEQ-1){
          int ci = (layer*1024 + b16 + g4*4 + q)*128 + j;
          carryH[ci] = hh;
          carryC[ci] = cn;
        }
      }
      __syncthreads();
      cur ^= 1;
    }
    __syncthreads();
  }
}

// ---- streamed decoder gate GEMM: depth-2 rotating queue, all indices static.
// wave w8 owns ntiles {g*8 + w8}; K=256 = [A0 | A1]. Peak live ~110 VGPRs.
#define LDQ(Q, g, kh) \
  Q[0] = wb[(size_t)((g)*64 + (kh)*4 + 0)*64]; \
  Q[1] = wb[(size_t)((g)*64 + (kh)*4 + 1)*64]; \
  Q[2] = wb[(size_t)((g)*64 + (kh)*4 + 2)*64]; \
  Q[3] = wb[(size_t)((g)*64 + (kh)*4 + 3)*64];
#define MM4(Q, A, g) \
  acc[g] = MFMA(A[0], Q[0], acc[g], 0,0,0); \
  acc[g] = MFMA(A[1], Q[1], acc[g], 0,0,0); \
  acc[g] = MFMA(A[2], Q[2], acc[g], 0,0,0); \
  acc[g] = MFMA(A[3], Q[3], acc[g], 0,0,0);

static __device__ __forceinline__ void dec_gemm(const __half* __restrict__ W,
    const __half* __restrict__ A0, const __half* __restrict__ A1,
    f32x4* acc, int lane, int w8)
{
  const f16x8* wb = (const f16x8*)W + (size_t)(w8*8)*64 + lane;
  f16x8 qA[4], qB[4], a0[4], a1[4];
  LDQ(qA, 0, 0)
  LDQ(qB, 1, 0)
#pragma unroll
  for (int kt=0; kt<4; ++kt) a0[kt] = *(const f16x8*)(A0 + (kt*64+lane)*8);
#pragma unroll
  for (int g=0; g<4; ++g) acc[g] = (f32x4){0.f,0.f,0.f,0.f};
  MM4(qA, a0, 0)  LDQ(qA, 2, 0)
  MM4(qB, a0, 1)  LDQ(qB, 3, 0)
#pragma unroll
  for (int kt=0; kt<4; ++kt) a1[kt] = *(const f16x8*)(A1 + (kt*64+lane)*8);
  MM4(qA, a0, 2)  LDQ(qA, 0, 1)
  MM4(qB, a0, 3)  LDQ(qB, 1, 1)
  MM4(qA, a1, 0)  LDQ(qA, 2, 1)
  MM4(qB, a1, 1)  LDQ(qB, 3, 1)
  MM4(qA, a1, 2)
  MM4(qB, a1, 3)
}

// ---------------- decoder: 512 blocks x 512 thr, 2 batch rows each ----------------
// LDS ~52 KB/block -> 2 blocks/CU -> 4 waves/SIMD (latency overlap across blocks).
__global__ __launch_bounds__(512) __attribute__((amdgpu_waves_per_eu(2, 2)))
void dec_kernel(
    const float* __restrict__ prev_y, const float* __restrict__ db0,
    const float* __restrict__ db12, const float* __restrict__ ob,
    const float* __restrict__ ab, const float* __restrict__ vW,
    const __half* __restrict__ wD0, const __half* __restrict__ wD1,
    const __half* __restrict__ wD2, const __half* __restrict__ wAh,
    const __half* __restrict__ wAeF, const float* __restrict__ wOT,
    const float* __restrict__ dW2, const __half* __restrict__ encAg,
    const __half* __restrict__ carryH, const float* __restrict__ carryC,
    float* __restrict__ dout)
{
  // hT: 0=weighted, 1=h0, 2=h1, 3=h2 (M=16 tiles, rows 0-1 real)
  __shared__ __align__(16) __half hT[4][2048];
  __shared__ float hp[2][132];
  __shared__ float scbF[128];
  __shared__ __align__(16) __half scb16h[128];
  __shared__ float po[2][2];
  __shared__ float vwl[128];
  extern __shared__ __align__(16) __half dyn[];
  __half* epL = dyn;                                // [128][132] f16

  const int tid = threadIdx.x, w = tid>>6, lane = tid&63;
  const int l15 = lane&15, g4 = lane>>4;
  const int d = blockIdx.x, b2 = d*2;
  const int w8 = (w + d) & 7;                       // wave-slice decorrelation
  const int j = w8*16 + l15;                        // this wave's column slice
  const int K0 = ((j>>5)*64 + ((j>>3)&3)*16)*8 + (j&7);
  // encA row blocks for batch rows b2, b2+1 (8192 halfs each, within enc layout)
  const __half* encR0 = encAg + (size_t)(b2>>4)*131072
                      + (size_t)((b2&15)>>2)*32768 + (size_t)(b2&3)*8192;

  // ---- carry + constants ----
  float cD[3][2];
  if (g4 == 0){
#pragma unroll
    for (int l=0; l<3; ++l)
#pragma unroll
      for (int q=0; q<2; ++q){
        int ci = (l*1024 + b2 + q)*128 + j;
        hT[1+l][K0 + q*8] = carryH[ci];
        cD[l][q] = carryC[ci];
      }
  }
  if (tid < 4) po[tid>>1][tid&1] = prev_y[(b2 + (tid>>1))*2 + (tid&1)];
  if (tid < 128) vwl[tid] = vW[tid];

  // ---- weighted-GEMM B-frags (t-invariant): gather once into registers ----
  f16x8 eBr[2][2];
#pragma unroll
  for (int rr=0; rr<2; ++rr)
#pragma unroll
    for (int kt=0; kt<2; ++kt){
      int bs = kt*32 + g4*8;                        // k base for this lane
      const __half* src = encR0 + rr*8192 + (bs>>4)*2048 + (j>>5)*512
                        + ((bs&15) + ((j>>3)&3)*16)*8 + (j&7);
      f16x8 v;
#pragma unroll
      for (int u=0; u<8; ++u) v[u] = (f16)src[(size_t)u*8];
      eBr[rr][kt] = v;
    }

  // ---- ep = enc_out @ attn_W_enc^T + ab  (MFMA; wave w owns mtile w) ----
  {
    int rr = w>>2, sb = w&3;
    const __half* arow = encR0 + rr*8192 + sb*2048;
    f16x8 a[4];
#pragma unroll
    for (int kt=0; kt<4; ++kt) a[kt] = *(const f16x8*)(arow + (kt*64+lane)*8);
    const f16x8* bw = (const f16x8*)wAeF + lane;
#pragma unroll
    for (int nt=0; nt<8; ++nt){
      int col = nt*16 + l15;
      float abv = ab[col];
      f32x4 acc = {abv, abv, abv, abv};
#pragma unroll
      for (int kt=0; kt<4; ++kt) acc = MFMA(a[kt], bw[(size_t)(nt*4+kt)*64], acc, 0,0,0);
      int srow = rr*64 + sb*16 + g4*4;
#pragma unroll
      for (int q=0; q<4; ++q) epL[(srow+q)*132 + col] = __float2half(acc[q]);
    }
  }
  __syncthreads();

  // LSTM cell pointwise, rows 0-1 (g4==0 lanes); consts loaded per-call.
  auto cell = [&](float* crl, const float* bdp, const float* dwp, __half* hdst,
                  const f32x4* acc){
    float b0 = bdp[j], b1 = bdp[128+j], b2_ = bdp[256+j], b3 = bdp[384+j];
    float2 w0, w1, w2, w3;
    if (dwp){
      w0 = *(const float2*)(dwp + 2*j);
      w1 = *(const float2*)(dwp + 2*(128+j));
      w2 = *(const float2*)(dwp + 2*(256+j));
      w3 = *(const float2*)(dwp + 2*(384+j));
    }
#pragma unroll
    for (int q=0; q<2; ++q){
      float gi = acc[0][q]+b0, gf = acc[1][q]+b1, gg = acc[2][q]+b2_, go = acc[3][q]+b3;
      if (dwp){
        float p0 = po[q][0], p1 = po[q][1];
        gi += p0*w0.x + p1*w0.y;
        gf += p0*w1.x + p1*w1.y;
        gg += p0*w2.x + p1*w2.y;
        go += p0*w3.x + p1*w3.y;
      }
      float cn = fmaf(sigm(gf), crl[q], sigm(gi)*tanh_fast(gg));
      float hn = sigm(go)*tanh_fast(cn);
      crl[q] = cn;
      hdst[K0 + q*8] = __float2half(hn);
    }
  };

  // ---- 24 autoregressive steps ----
  int zr = 0;
  for (int t=0; t<TOUT; ++t){
    asm volatile("" : "+v"(zr));                 // opaque 0: defeats LICM hoisting
    const float*  db0t  = db0  + zr;
    const float*  db12t = db12 + zr;
    const float*  dW2t  = dW2  + zr;
    const __half* wAht  = wAh  + zr;

    { // hproj = h2 @ attn_Wh (wAh frags loaded per step, transient regs)
      f16x8 a[4], wAhR[4];
      const f16x8* wbh = (const f16x8*)wAht + lane;
#pragma unroll
      for (int kt=0; kt<4; ++kt) wAhR[kt] = wbh[(size_t)(w8*4+kt)*64];
#pragma unroll
      for (int kt=0; kt<4; ++kt) a[kt] = *(const f16x8*)(hT[3] + (kt*64+lane)*8);
      f32x4 acc = {0.f,0.f,0.f,0.f};
#pragma unroll
      for (int kt=0; kt<4; ++kt) acc = MFMA(a[kt], wAhR[kt], acc, 0,0,0);
      if (g4 == 0){
        hp[0][j] = acc[0];
        hp[1][j] = acc[1];
      }
    }
    __syncthreads();
    { // scores: 128 (r,s) pairs x 4 threads each (32 j-elements per thread)
      int rs = tid>>2, jq = tid&3, r = rs>>6;
      const __half* er = epL + rs*132 + jq*32;
      const float* hr = hp[r] + jq*32;
      const float* vr = vwl + jq*32;
      float sc = 0.f;
#pragma unroll
      for (int p=0; p<4; ++p){
        f16x8 e = *(const f16x8*)(er + p*8);
#pragma unroll
        for (int u=0; u<8; ++u)
          sc = fmaf(tanh_fast((float)e[u] + hr[p*8+u]), vr[p*8+u], sc);
      }
      sc += __shfl_xor(sc, 1);
      sc += __shfl_xor(sc, 2);
      if (jq == 0) scbF[rs] = sc;
    }
    __syncthreads();
    if (tid < 128){ // softmax over s per row (wave = row)
      float v = scbF[tid];
      float m = v;
#pragma unroll
      for (int off=32; off; off>>=1) m = fmaxf(m, __shfl_xor(m, off));
      float e = __expf(v - m);
      float sm = e;
#pragma unroll
      for (int off=32; off; off>>=1) sm += __shfl_xor(sm, off);
      scb16h[tid] = __float2half(e * __builtin_amdgcn_rcpf(sm));
    }
    __syncthreads();
    { // weighted = attw @ enc_out via MFMA (A = broadcast attw row; B in regs)
#pragma unroll
      for (int rr=0; rr<2; ++rr){
        f32x4 acc = {0.f,0.f,0.f,0.f};
#pragma unroll
        for (int kt=0; kt<2; ++kt){
          f16x8 abc = *(const f16x8*)(scb16h + rr*64 + kt*32 + g4*8);
          acc = MFMA(abc, eBr[rr][kt], acc, 0,0,0);
        }
        if (lane < 16) hT[0][K0 + rr*8] = __float2half(acc[0]);
      }
    }
    __syncthreads();
    f32x4 acc[4];
    dec_gemm(wD0, hT[0], hT[1], acc, lane, w8);
    __syncthreads();
    if (g4 == 0) cell(cD[0], db0t, dW2t, hT[1], acc);
    __syncthreads();
    dec_gemm(wD1, hT[1], hT[2], acc, lane, w8);
    __syncthreads();
    if (g4 == 0) cell(cD[1], db12t, nullptr, hT[2], acc);
    __syncthreads();
    dec_gemm(wD2, hT[2], hT[3], acc, lane, w8);
    __syncthreads();
    if (g4 == 0) cell(cD[2], db12t + 512, nullptr, hT[3], acc);
    __syncthreads();
    if (tid < 128){ // output head: row r from f16 frag tiles (h2 + weighted)
      int r = tid>>6, kl = tid&63;
      int k2 = kl*2;
      int sl = ((k2>>5)*64 + r + ((k2>>3)&3)*16)*8 + (k2&7);
      float2 h2f = __half22float2(*(const __half2*)(hT[3] + sl));
      float2 wwf = __half22float2(*(const __half2*)(hT[0] + sl));
      float2 a0 = *(const float2*)(wOT + k2*2);
      float2 a1 = *(const float2*)(wOT + k2*2 + 2);
      float2 b0v = *(const float2*)(wOT + (128+k2)*2);
      float2 b1v = *(const float2*)(wOT + (128+k2)*2 + 2);
      float o0 = h2f.x*a0.x + h2f.y*a1.x + wwf.x*b0v.x + wwf.y*b1v.x;
      float o1 = h2f.x*a0.y + h2f.y*a1.y + wwf.x*b0v.y + wwf.y*b1v.y;
#pragma unroll
      for (int off=32; off; off>>=1){ o0 += __shfl_xor(o0, off); o1 += __shfl_xor(o1, off); }
      if (kl == 0){
        float v0 = o0 + ob[0], v1 = o1 + ob[1];
        size_t oi = ((size_t)t*1024 + b2 + r)*2;
        dout[oi] = v0; dout[oi+1] = v1;
        po[r][0] = v0; po[r][1] = v1;
      }
    }
    __syncthreads();
  }
}

extern "C" void kernel_launch(void* const* d_in, const int* in_sizes, int n_in,
                              void* d_out, int out_size, void* d_ws, size_t ws_size,
                              hipStream_t stream) {
  const float* x      = (const float*)d_in[0];
  const float* prev_y = (const float*)d_in[1];
  const float* eWih0  = (const float*)d_in[2];
  const float* eWhh0  = (const float*)d_in[3];
  const float* eb0    = (const float*)d_in[4];
  const float* eWih12 = (const float*)d_in[5];
  const float* eWhh12 = (const float*)d_in[6];
  const float* eb12   = (const float*)d_in[7];
  const float* aW     = (const float*)d_in[8];
  const float* ab     = (const float*)d_in[9];
  const float* vW     = (const float*)d_in[10];
  const float* dWih0  = (const float*)d_in[11];
  const float* dWhh0  = (const float*)d_in[12];
  const float* db0    = (const float*)d_in[13];
  const float* dWih12 = (const float*)d_in[14];
  const float* dWhh12 = (const float*)d_in[15];
  const float* db12   = (const float*)d_in[16];
  const float* oW     = (const float*)d_in[17];
  const float* ob     = (const float*)d_in[18];

  __half* wE0  = (__half*)d_ws;            // 65536
  __half* wE1  = wE0 + 65536;              // 131072 each
  __half* wE2  = wE1 + 131072;
  __half* wD0  = wE2 + 131072;
  __half* wD1  = wD0 + 131072;
  __half* wD2  = wD1 + 131072;
  __half* wAh  = wD2 + 131072;             // 16384
  __half* wAeF = wAh + 16384;              // 16384
  float*  wOT  = (float*)(wAeF + 16384);   // 512 f32
  float*  dW2  = wOT + 512;                // 1024 f32
  __half* hs0  = (__half*)(dW2 + 1024);    // 64 x 131072 halfs (16 MB); encA overlays
  __half* hs1  = hs0 + (size_t)64*131072;  // 16 MB
  __half* carryH = hs1 + (size_t)64*131072;        // 393216 halfs
  float*  carryC = (float*)(carryH + 393216);      // 393216 f32

  const int prepN = 65536 + 5*131072 + 16384 + 16384 + 512 + 1024;
  prep_kernel<<<(prepN + 255)/256, 256, 0, stream>>>(
      eWih0, eWhh0, eWih12, eWhh12, aW, dWih0, dWhh0, dWih12, dWhh12, oW,
      wE0, wE1, wE2, wD0, wD1, wD2, wAh, wAeF, wOT, dW2);

  enc_kernel<<<64, 512, 0, stream>>>(
      x, eb0, eb12, eWih0, wE0, wE1, wE2, hs0, hs1, carryH, carryC);

  const int dynB = 128*132*2;              // epL = 33,792 B  (2 blocks/CU)
  hipFuncSetAttribute(reinterpret_cast<const void*>(dec_kernel),
                      hipFuncAttributeMaxDynamicSharedMemorySize, dynB);
  dec_kernel<<<512, 512, dynB, stream>>>(
      prev_y, db0, db12, ob, ab, vW, wD0, wD1, wD2, wAh, wAeF, wOT, dW2,
      hs0, carryH, carryC, (float*)d_out);
}

// Round 13
// 880.709 us; speedup vs baseline: 1.0016x; 1.0016x over previous
//
#include <hip/hip_runtime.h>
#include <hip/hip_fp16.h>

#define SEQ   64
#define HID   128
#define TOUT  24

typedef unsigned int u32;
typedef _Float16 f16;
typedef __attribute__((ext_vector_type(8))) f16 f16x8;
typedef __attribute__((ext_vector_type(4))) float f32x4;
#define MFMA __builtin_amdgcn_mfma_f32_16x16x32_f16

static __device__ __forceinline__ float sigm(float x){
  return __builtin_amdgcn_rcpf(1.f + __expf(-x));
}
static __device__ __forceinline__ float tanh_fast(float x){
  return fmaf(2.f, __builtin_amdgcn_rcpf(1.f + __expf(-2.f*x)), -1.f);
}

// ---------------- weight prep: fp32 -> MFMA B-fragment fp16 layouts (unchanged) ----
__global__ void prep_kernel(
    const float* __restrict__ eWih0,  const float* __restrict__ eWhh0,
    const float* __restrict__ eWih12, const float* __restrict__ eWhh12,
    const float* __restrict__ aW,
    const float* __restrict__ dWih0,  const float* __restrict__ dWhh0,
    const float* __restrict__ dWih12, const float* __restrict__ dWhh12,
    const float* __restrict__ oW,
    __half* __restrict__ wE0, __half* __restrict__ wE1, __half* __restrict__ wE2,
    __half* __restrict__ wD0, __half* __restrict__ wD1, __half* __restrict__ wD2,
    __half* __restrict__ wAh, __half* __restrict__ wAeF, float* __restrict__ wOT,
    float* __restrict__ dW2)
{
  int id = blockIdx.x*blockDim.x + threadIdx.x;
  if (id < 65536){                                   // wE0: K=128 (Whh only), KT=4
    int m=id, jj=m&7, l=(m>>3)&63, kt=(m>>9)&3, nt=m>>11;
    int col = nt*16 + (l&15), k = kt*32 + ((l>>4)<<3) + jj;
    wE0[m] = __float2half(eWhh0[col*128 + k]); return;
  }
  id -= 65536;
  if (id < 5*131072){                                // wE1,wE2,wD0,wD1,wD2: K=256, KT=8
    int seg = id >> 17, m = id & 131071;
    int jj=m&7, l=(m>>3)&63, kt=(m>>9)&7, nt=m>>12;
    int col = nt*16 + (l&15), k = kt*32 + ((l>>4)<<3) + jj;
    float v;
    if (seg==0)      v = (k<128)? eWih12[col*128+k]         : eWhh12[col*128 + (k-128)];
    else if (seg==1) v = (k<128)? eWih12[65536+col*128+k]   : eWhh12[65536 + col*128 + (k-128)];
    else if (seg==2) v = (k<128)? dWih0[col*130 + 2 + k]    : dWhh0[col*128 + (k-128)];
    else if (seg==3) v = (k<128)? dWih12[col*128+k]         : dWhh12[col*128 + (k-128)];
    else             v = (k<128)? dWih12[65536+col*128+k]   : dWhh12[65536 + col*128 + (k-128)];
    __half* dst = (seg==0)?wE1:(seg==1)?wE2:(seg==2)?wD0:(seg==3)?wD1:wD2;
    dst[m] = __float2half(v); return;
  }
  id -= 5*131072;
  if (id < 16384){                                   // wAh: attn_W[:, :H], KT=4, NT=8
    int m=id, jj=m&7, l=(m>>3)&63, kt=(m>>9)&3, nt=m>>11;
    int col = nt*16 + (l&15), k = kt*32 + ((l>>4)<<3) + jj;
    wAh[m] = __float2half(aW[col*256 + k]); return;
  }
  id -= 16384;
  if (id < 16384){                                   // wAeF: attn_W[:, H:], B-frags
    int m=id, jj=m&7, l=(m>>3)&63, kt=(m>>9)&3, nt=m>>11;
    int col = nt*16 + (l&15), k = kt*32 + ((l>>4)<<3) + jj;
    wAeF[m] = __float2half(aW[col*256 + 128 + k]); return;
  }
  id -= 16384;
  if (id < 512){ int k=id>>1, jo=id&1; wOT[id] = oW[jo*256 + k]; return; }   // [k][2] f32
  id -= 512;
  if (id < 1024){ int col=id>>1, ki=id&1; dW2[id] = dWih0[col*130 + ki]; return; } // [n][2]
}

// ---------------- encoder: 64 blocks x 512 thr, M=16 batch rows (byte-identical) ----
__global__ __launch_bounds__(512) __attribute__((amdgpu_waves_per_eu(2, 2)))
void enc_kernel(
    const float* __restrict__ x, const float* __restrict__ eb0,
    const float* __restrict__ eb12, const float* __restrict__ eWih0,
    const __half* __restrict__ wE0, const __half* __restrict__ wE1,
    const __half* __restrict__ wE2,
    __half* __restrict__ hs0, __half* __restrict__ hs1,
    __half* __restrict__ carryH, float* __restrict__ carryC)
{
  __shared__ __align__(16) __half hT[2][2048];

  const int tid = threadIdx.x, w = tid>>6, lane = tid&63;
  const int l15 = lane&15, g4 = lane>>4;
  const int j = w*16 + l15;
  const int b16 = blockIdx.x*16;
  const int K0 = ((j>>5)*64 + ((j>>3)&3)*16)*8 + (j&7);

  __half* hs0b = hs0 + (size_t)blockIdx.x*131072;
  __half* hs1b = hs1 + (size_t)blockIdx.x*131072;

  for (int layer=0; layer<3; ++layer){
    const __half* W  = (layer==0)? wE0 : (layer==1)? wE1 : wE2;
    const float* bs  = (layer==0)? eb0 : (layer==1)? eb12 : (eb12+512);
    const __half* hinb  = (layer==1)? hs0b : hs1b;     // valid for layer>0
    __half* houtb = (layer==0)? hs0b : (layer==1)? hs1b : nullptr;

    float bias[4];
#pragma unroll
    for (int g=0; g<4; ++g) bias[g] = bs[g*128 + j];
    float2 wx[4];
    if (layer==0){
#pragma unroll
      for (int g=0; g<4; ++g) wx[g] = *(const float2*)(eWih0 + (g*128+j)*2);
    }
    const f16x8* wb = (const f16x8*)W + lane;
    f16x8 Wh[16];                                    // resident W_hh slice
    if (layer==0){
#pragma unroll
      for (int g=0; g<4; ++g)
#pragma unroll
        for (int kt=0; kt<4; ++kt) Wh[g*4+kt] = wb[(size_t)((g*8+w)*4 + kt)*64];
    } else {
#pragma unroll
      for (int g=0; g<4; ++g)
#pragma unroll
        for (int kt=0; kt<4; ++kt) Wh[g*4+kt] = wb[(size_t)((g*8+w)*8 + 4 + kt)*64];
    }
    float c[4] = {0.f,0.f,0.f,0.f};
    ((u32*)hT[0])[tid] = 0u; ((u32*)hT[0])[tid+512] = 0u;
    __syncthreads();

    float2 xv[4]; f16x8 alo[4];
    if (layer==0){
#pragma unroll
      for (int q=0; q<4; ++q) xv[q] = *(const float2*)(x + ((size_t)(b16+g4*4+q)*SEQ + 0)*2);
    } else {
#pragma unroll
      for (int kt=0; kt<4; ++kt) alo[kt] = *(const f16x8*)(hinb + (kt*64+lane)*8);
    }

    int cur = 0;
    for (int t=0; t<SEQ; ++t){
      f16x8 wi[16];
      if (layer>0){                                  // stream W_ih slice (L2)
#pragma unroll
        for (int g=0; g<4; ++g)
#pragma unroll
          for (int kt=0; kt<4; ++kt) wi[g*4+kt] = wb[(size_t)((g*8+w)*8 + kt)*64];
      }
      f16x8 ah[4];
#pragma unroll
      for (int kt=0; kt<4; ++kt) ah[kt] = *(const f16x8*)(hT[cur] + (kt*64+lane)*8);
      float2 xcur[4]; f16x8 acur[4];
      if (layer==0){
#pragma unroll
        for (int q=0; q<4; ++q) xcur[q] = xv[q];
        if (t+1 < SEQ)
#pragma unroll
          for (int q=0; q<4; ++q) xv[q] = *(const float2*)(x + ((size_t)(b16+g4*4+q)*SEQ + t+1)*2);
      } else {
#pragma unroll
        for (int kt=0; kt<4; ++kt) acur[kt] = alo[kt];
        if (t+1 < SEQ)
#pragma unroll
          for (int kt=0; kt<4; ++kt) alo[kt] = *(const f16x8*)(hinb + (size_t)(t+1)*2048 + (kt*64+lane)*8);
      }
      f32x4 acc[4];
#pragma unroll
      for (int g=0; g<4; ++g) acc[g] = (f32x4){0.f,0.f,0.f,0.f};
#pragma unroll
      for (int g=0; g<4; ++g)
#pragma unroll
        for (int kt=0; kt<4; ++kt) acc[g] = MFMA(ah[kt], Wh[g*4+kt], acc[g], 0,0,0);
      if (layer>0){
#pragma unroll
        for (int g=0; g<4; ++g)
#pragma unroll
          for (int kt=0; kt<4; ++kt) acc[g] = MFMA(acur[kt], wi[g*4+kt], acc[g], 0,0,0);
      }
      // pointwise (all 16 rows)
#pragma unroll
      for (int q=0; q<4; ++q){
        float gi = acc[0][q]+bias[0], gf = acc[1][q]+bias[1],
              gg = acc[2][q]+bias[2], go = acc[3][q]+bias[3];
        if (layer==0){
          gi += xcur[q].x*wx[0].x + xcur[q].y*wx[0].y;
          gf += xcur[q].x*wx[1].x + xcur[q].y*wx[1].y;
          gg += xcur[q].x*wx[2].x + xcur[q].y*wx[2].y;
          go += xcur[q].x*wx[3].x + xcur[q].y*wx[3].y;
        }
        float cn = fmaf(sigm(gf), c[q], sigm(gi)*tanh_fast(gg));
        float hn = sigm(go)*tanh_fast(cn);
        c[q] = cn;
        __half hh = __float2half(hn);
        hT[cur^1][K0 + (g4*4+q)*8] = hh;
        if (layer < 2){
          houtb[(size_t)t*2048 + K0 + (g4*4+q)*8] = hh;
        } else {
          // encA overlay on hs0b: [d_local=g4][r4=q][sb=t>>4][ktA=j>>5][laneA][u]
          int off = g4*32768 + q*8192 + (t>>4)*2048 + (j>>5)*512
                  + ((t&15) + ((j>>3)&3)*16)*8 + (j&7);
          hs0b[off] = hh;
        }
        if (t == SEQ-1){
          int ci = (layer*1024 + b16 + g4*4 + q)*128 + j;
          carryH[ci] = hh;
          carryC[ci] = cn;
        }
      }
      __syncthreads();
      cur ^= 1;
    }
    __syncthreads();
  }
}

// ---- streamed decoder gate GEMM: depth-2 rotating queue, all indices static.
// wave w8 owns ntiles {g*8 + w8}; K=256 = [A0 | A1]. Peak live ~110 VGPRs.
#define LDQ(Q, g, kh) \
  Q[0] = wb[(size_t)((g)*64 + (kh)*4 + 0)*64]; \
  Q[1] = wb[(size_t)((g)*64 + (kh)*4 + 1)*64]; \
  Q[2] = wb[(size_t)((g)*64 + (kh)*4 + 2)*64]; \
  Q[3] = wb[(size_t)((g)*64 + (kh)*4 + 3)*64];
#define MM4(Q, A, g) \
  acc[g] = MFMA(A[0], Q[0], acc[g], 0,0,0); \
  acc[g] = MFMA(A[1], Q[1], acc[g], 0,0,0); \
  acc[g] = MFMA(A[2], Q[2], acc[g], 0,0,0); \
  acc[g] = MFMA(A[3], Q[3], acc[g], 0,0,0);

static __device__ __forceinline__ void dec_gemm(const __half* __restrict__ W,
    const __half* __restrict__ A0, const __half* __restrict__ A1,
    f32x4* acc, int lane, int w8)
{
  const f16x8* wb = (const f16x8*)W + (size_t)(w8*8)*64 + lane;
  f16x8 qA[4], qB[4], a0[4], a1[4];
  LDQ(qA, 0, 0)
  LDQ(qB, 1, 0)
#pragma unroll
  for (int kt=0; kt<4; ++kt) a0[kt] = *(const f16x8*)(A0 + (kt*64+lane)*8);
#pragma unroll
  for (int g=0; g<4; ++g) acc[g] = (f32x4){0.f,0.f,0.f,0.f};
  MM4(qA, a0, 0)  LDQ(qA, 2, 0)
  MM4(qB, a0, 1)  LDQ(qB, 3, 0)
#pragma unroll
  for (int kt=0; kt<4; ++kt) a1[kt] = *(const f16x8*)(A1 + (kt*64+lane)*8);
  MM4(qA, a0, 2)  LDQ(qA, 0, 1)
  MM4(qB, a0, 3)  LDQ(qB, 1, 1)
  MM4(qA, a1, 0)  LDQ(qA, 2, 1)
  MM4(qB, a1, 1)  LDQ(qB, 3, 1)
  MM4(qA, a1, 2)
  MM4(qB, a1, 3)
}

// ---------------- decoder: 512 blocks x 512 thr, 2 batch rows each ----------------
// LDS ~52 KB/block; NO waves_per_eu cap -> 2 blocks/CU co-resident (VGPR-limited).
__global__ __launch_bounds__(512)
void dec_kernel(
    const float* __restrict__ prev_y, const float* __restrict__ db0,
    const float* __restrict__ db12, const float* __restrict__ ob,
    const float* __restrict__ ab, const float* __restrict__ vW,
    const __half* __restrict__ wD0, const __half* __restrict__ wD1,
    const __half* __restrict__ wD2, const __half* __restrict__ wAh,
    const __half* __restrict__ wAeF, const float* __restrict__ wOT,
    const float* __restrict__ dW2, const __half* __restrict__ encAg,
    const __half* __restrict__ carryH, const float* __restrict__ carryC,
    float* __restrict__ dout)
{
  // hT: 0=weighted, 1=h0, 2=h1, 3=h2 (M=16 tiles, rows 0-1 real)
  __shared__ __align__(16) __half hT[4][2048];
  __shared__ float hp[2][132];
  __shared__ float scbF[128];
  __shared__ __align__(16) __half scb16h[128];
  __shared__ float po[2][2];
  __shared__ float vwl[128];
  extern __shared__ __align__(16) __half dyn[];
  __half* epL = dyn;                                // [128][132] f16

  const int tid = threadIdx.x, w = tid>>6, lane = tid&63;
  const int l15 = lane&15, g4 = lane>>4;
  const int d = blockIdx.x, b2 = d*2;
  const int w8 = (w + d) & 7;                       // wave-slice decorrelation
  const int j = w8*16 + l15;                        // this wave's column slice
  const int K0 = ((j>>5)*64 + ((j>>3)&3)*16)*8 + (j&7);
  // encA row blocks for batch rows b2, b2+1 (8192 halfs each, within enc layout)
  const __half* encR0 = encAg + (size_t)(b2>>4)*131072
                      + (size_t)((b2&15)>>2)*32768 + (size_t)(b2&3)*8192;

  // ---- carry + constants ----
  float cD[3][2];
  if (g4 == 0){
#pragma unroll
    for (int l=0; l<3; ++l)
#pragma unroll
      for (int q=0; q<2; ++q){
        int ci = (l*1024 + b2 + q)*128 + j;
        hT[1+l][K0 + q*8] = carryH[ci];
        cD[l][q] = carryC[ci];
      }
  }
  if (tid < 4) po[tid>>1][tid&1] = prev_y[(b2 + (tid>>1))*2 + (tid&1)];
  if (tid < 128) vwl[tid] = vW[tid];

  // ---- weighted-GEMM B-frags (t-invariant): gather once into registers ----
  f16x8 eBr[2][2];
#pragma unroll
  for (int rr=0; rr<2; ++rr)
#pragma unroll
    for (int kt=0; kt<2; ++kt){
      int bs = kt*32 + g4*8;                        // k base for this lane
      const __half* src = encR0 + rr*8192 + (bs>>4)*2048 + (j>>5)*512
                        + ((bs&15) + ((j>>3)&3)*16)*8 + (j&7);
      f16x8 v;
#pragma unroll
      for (int u=0; u<8; ++u) v[u] = (f16)src[(size_t)u*8];
      eBr[rr][kt] = v;
    }

  // ---- ep = enc_out @ attn_W_enc^T + ab  (MFMA; wave w owns mtile w) ----
  {
    int rr = w>>2, sb = w&3;
    const __half* arow = encR0 + rr*8192 + sb*2048;
    f16x8 a[4];
#pragma unroll
    for (int kt=0; kt<4; ++kt) a[kt] = *(const f16x8*)(arow + (kt*64+lane)*8);
    const f16x8* bw = (const f16x8*)wAeF + lane;
#pragma unroll
    for (int nt=0; nt<8; ++nt){
      int col = nt*16 + l15;
      float abv = ab[col];
      f32x4 acc = {abv, abv, abv, abv};
#pragma unroll
      for (int kt=0; kt<4; ++kt) acc = MFMA(a[kt], bw[(size_t)(nt*4+kt)*64], acc, 0,0,0);
      int srow = rr*64 + sb*16 + g4*4;
#pragma unroll
      for (int q=0; q<4; ++q) epL[(srow+q)*132 + col] = __float2half(acc[q]);
    }
  }
  __syncthreads();

  // LSTM cell pointwise, rows 0-1 (g4==0 lanes); consts loaded per-call.
  auto cell = [&](float* crl, const float* bdp, const float* dwp, __half* hdst,
                  const f32x4* acc){
    float b0 = bdp[j], b1 = bdp[128+j], b2_ = bdp[256+j], b3 = bdp[384+j];
    float2 w0, w1, w2, w3;
    if (dwp){
      w0 = *(const float2*)(dwp + 2*j);
      w1 = *(const float2*)(dwp + 2*(128+j));
      w2 = *(const float2*)(dwp + 2*(256+j));
      w3 = *(const float2*)(dwp + 2*(384+j));
    }
#pragma unroll
    for (int q=0; q<2; ++q){
      float gi = acc[0][q]+b0, gf = acc[1][q]+b1, gg = acc[2][q]+b2_, go = acc[3][q]+b3;
      if (dwp){
        float p0 = po[q][0], p1 = po[q][1];
        gi += p0*w0.x + p1*w0.y;
        gf += p0*w1.x + p1*w1.y;
        gg += p0*w2.x + p1*w2.y;
        go += p0*w3.x + p1*w3.y;
      }
      float cn = fmaf(sigm(gf), crl[q], sigm(gi)*tanh_fast(gg));
      float hn = sigm(go)*tanh_fast(cn);
      crl[q] = cn;
      hdst[K0 + q*8] = __float2half(hn);
    }
  };

  // ---- 24 autoregressive steps ----
  int zr = 0;
  for (int t=0; t<TOUT; ++t){
    asm volatile("" : "+v"(zr));                 // opaque 0: defeats LICM hoisting
    const float*  db0t  = db0  + zr;
    const float*  db12t = db12 + zr;
    const float*  dW2t  = dW2  + zr;
    const __half* wAht  = wAh  + zr;

    { // hproj = h2 @ attn_Wh (wAh frags loaded per step, transient regs)
      f16x8 a[4], wAhR[4];
      const f16x8* wbh = (const f16x8*)wAht + lane;
#pragma unroll
      for (int kt=0; kt<4; ++kt) wAhR[kt] = wbh[(size_t)(w8*4+kt)*64];
#pragma unroll
      for (int kt=0; kt<4; ++kt) a[kt] = *(const f16x8*)(hT[3] + (kt*64+lane)*8);
      f32x4 acc = {0.f,0.f,0.f,0.f};
#pragma unroll
      for (int kt=0; kt<4; ++kt) acc = MFMA(a[kt], wAhR[kt], acc, 0,0,0);
      if (g4 == 0){
        hp[0][j] = acc[0];
        hp[1][j] = acc[1];
      }
    }
    __syncthreads();
    { // scores: 128 (r,s) pairs x 4 threads each (32 j-elements per thread)
      int rs = tid>>2, jq = tid&3, r = rs>>6;
      const __half* er = epL + rs*132 + jq*32;
      const float* hr = hp[r] + jq*32;
      const float* vr = vwl + jq*32;
      float sc = 0.f;
#pragma unroll
      for (int p=0; p<4; ++p){
        f16x8 e = *(const f16x8*)(er + p*8);
#pragma unroll
        for (int u=0; u<8; ++u)
          sc = fmaf(tanh_fast((float)e[u] + hr[p*8+u]), vr[p*8+u], sc);
      }
      sc += __shfl_xor(sc, 1);
      sc += __shfl_xor(sc, 2);
      if (jq == 0) scbF[rs] = sc;
    }
    __syncthreads();
    if (tid < 128){ // softmax over s per row (wave = row)
      float v = scbF[tid];
      float m = v;
#pragma unroll
      for (int off=32; off; off>>=1) m = fmaxf(m, __shfl_xor(m, off));
      float e = __expf(v - m);
      float sm = e;
#pragma unroll
      for (int off=32; off; off>>=1) sm += __shfl_xor(sm, off);
      scb16h[tid] = __float2half(e * __builtin_amdgcn_rcpf(sm));
    }
    __syncthreads();
    { // weighted = attw @ enc_out via MFMA (A = broadcast attw row; B in regs)
#pragma unroll
      for (int rr=0; rr<2; ++rr){
        f32x4 acc = {0.f,0.f,0.f,0.f};
#pragma unroll
        for (int kt=0; kt<2; ++kt){
          f16x8 abc = *(const f16x8*)(scb16h + rr*64 + kt*32 + g4*8);
          acc = MFMA(abc, eBr[rr][kt], acc, 0,0,0);
        }
        if (lane < 16) hT[0][K0 + rr*8] = __float2half(acc[0]);
      }
    }
    __syncthreads();
    f32x4 acc[4];
    dec_gemm(wD0, hT[0], hT[1], acc, lane, w8);
    __syncthreads();
    if (g4 == 0) cell(cD[0], db0t, dW2t, hT[1], acc);
    __syncthreads();
    dec_gemm(wD1, hT[1], hT[2], acc, lane, w8);
    __syncthreads();
    if (g4 == 0) cell(cD[1], db12t, nullptr, hT[2], acc);
    __syncthreads();
    dec_gemm(wD2, hT[2], hT[3], acc, lane, w8);
    __syncthreads();
    if (g4 == 0) cell(cD[2], db12t + 512, nullptr, hT[3], acc);
    __syncthreads();
    if (tid < 128){ // output head: row r from f16 frag tiles (h2 + weighted)
      int r = tid>>6, kl = tid&63;
      int k2 = kl*2;
      int sl = ((k2>>5)*64 + r + ((k2>>3)&3)*16)*8 + (k2&7);
      float2 h2f = __half22float2(*(const __half2*)(hT[3] + sl));
      float2 wwf = __half22float2(*(const __half2*)(hT[0] + sl));
      float2 a0 = *(const float2*)(wOT + k2*2);
      float2 a1 = *(const float2*)(wOT + k2*2 + 2);
      float2 b0v = *(const float2*)(wOT + (128+k2)*2);
      float2 b1v = *(const float2*)(wOT + (128+k2)*2 + 2);
      float o0 = h2f.x*a0.x + h2f.y*a1.x + wwf.x*b0v.x + wwf.y*b1v.x;
      float o1 = h2f.x*a0.y + h2f.y*a1.y + wwf.x*b0v.y + wwf.y*b1v.y;
#pragma unroll
      for (int off=32; off; off>>=1){ o0 += __shfl_xor(o0, off); o1 += __shfl_xor(o1, off); }
      if (kl == 0){
        float v0 = o0 + ob[0], v1 = o1 + ob[1];
        size_t oi = ((size_t)t*1024 + b2 + r)*2;
        dout[oi] = v0; dout[oi+1] = v1;
        po[r][0] = v0; po[r][1] = v1;
      }
    }
    __syncthreads();
  }
}

extern "C" void kernel_launch(void* const* d_in, const int* in_sizes, int n_in,
                              void* d_out, int out_size, void* d_ws, size_t ws_size,
                              hipStream_t stream) {
  const float* x      = (const float*)d_in[0];
  const float* prev_y = (const float*)d_in[1];
  const float* eWih0  = (const float*)d_in[2];
  const float* eWhh0  = (const float*)d_in[3];
  const float* eb0    = (const float*)d_in[4];
  const float* eWih12 = (const float*)d_in[5];
  const float* eWhh12 = (const float*)d_in[6];
  const float* eb12   = (const float*)d_in[7];
  const float* aW     = (const float*)d_in[8];
  const float* ab     = (const float*)d_in[9];
  const float* vW     = (const float*)d_in[10];
  const float* dWih0  = (const float*)d_in[11];
  const float* dWhh0  = (const float*)d_in[12];
  const float* db0    = (const float*)d_in[13];
  const float* dWih12 = (const float*)d_in[14];
  const float* dWhh12 = (const float*)d_in[15];
  const float* db12   = (const float*)d_in[16];
  const float* oW     = (const float*)d_in[17];
  const float* ob     = (const float*)d_in[18];

  __half* wE0  = (__half*)d_ws;            // 65536
  __half* wE1  = wE0 + 65536;              // 131072 each
  __half* wE2  = wE1 + 131072;
  __half* wD0  = wE2 + 131072;
  __half* wD1  = wD0 + 131072;
  __half* wD2  = wD1 + 131072;
  __half* wAh  = wD2 + 131072;             // 16384
  __half* wAeF = wAh + 16384;              // 16384
  float*  wOT  = (float*)(wAeF + 16384);   // 512 f32
  float*  dW2  = wOT + 512;                // 1024 f32
  __half* hs0  = (__half*)(dW2 + 1024);    // 64 x 131072 halfs (16 MB); encA overlays
  __half* hs1  = hs0 + (size_t)64*131072;  // 16 MB
  __half* carryH = hs1 + (size_t)64*131072;        // 393216 halfs
  float*  carryC = (float*)(carryH + 393216);      // 393216 f32

  const int prepN = 65536 + 5*131072 + 16384 + 16384 + 512 + 1024;
  prep_kernel<<<(prepN + 255)/256, 256, 0, stream>>>(
      eWih0, eWhh0, eWih12, eWhh12, aW, dWih0, dWhh0, dWih12, dWhh12, oW,
      wE0, wE1, wE2, wD0, wD1, wD2, wAh, wAeF, wOT, dW2);

  enc_kernel<<<64, 512, 0, stream>>>(
      x, eb0, eb12, eWih0, wE0, wE1, wE2, hs0, hs1, carryH, carryC);

  const int dynB = 128*132*2;              // epL = 33,792 B
  hipFuncSetAttribute(reinterpret_cast<const void*>(dec_kernel),
                      hipFuncAttributeMaxDynamicSharedMemorySize, dynB);
  dec_kernel<<<512, 512, dynB, stream>>>(
      prev_y, db0, db12, ob, ab, vW, wD0, wD1, wD2, wAh, wAeF, wOT, dW2,
      hs0, carryH, carryC, (float*)d_out);
}

// Round 14
// 615.394 us; speedup vs baseline: 1.4334x; 1.4311x over previous
//
#include <hip/hip_runtime.h>
#include <hip/hip_fp16.h>

#define SEQ   64
#define HID   128
#define TOUT  24

typedef unsigned int u32;
typedef _Float16 f16;
typedef __attribute__((ext_vector_type(8))) f16 f16x8;
typedef __attribute__((ext_vector_type(4))) float f32x4;
#define MFMA __builtin_amdgcn_mfma_f32_16x16x32_f16

static __device__ __forceinline__ float sigm(float x){
  return __builtin_amdgcn_rcpf(1.f + __expf(-x));
}
static __device__ __forceinline__ float tanh_fast(float x){
  return fmaf(2.f, __builtin_amdgcn_rcpf(1.f + __expf(-2.f*x)), -1.f);
}

// ---------------- weight prep: fp32 -> MFMA B-fragment fp16 layouts (unchanged) ----
__global__ void prep_kernel(
    const float* __restrict__ eWih0,  const float* __restrict__ eWhh0,
    const float* __restrict__ eWih12, const float* __restrict__ eWhh12,
    const float* __restrict__ aW,
    const float* __restrict__ dWih0,  const float* __restrict__ dWhh0,
    const float* __restrict__ dWih12, const float* __restrict__ dWhh12,
    const float* __restrict__ oW,
    __half* __restrict__ wE0, __half* __restrict__ wE1, __half* __restrict__ wE2,
    __half* __restrict__ wD0, __half* __restrict__ wD1, __half* __restrict__ wD2,
    __half* __restrict__ wAh, __half* __restrict__ wAeF, float* __restrict__ wOT,
    float* __restrict__ dW2)
{
  int id = blockIdx.x*blockDim.x + threadIdx.x;
  if (id < 65536){                                   // wE0: K=128 (Whh only), KT=4
    int m=id, jj=m&7, l=(m>>3)&63, kt=(m>>9)&3, nt=m>>11;
    int col = nt*16 + (l&15), k = kt*32 + ((l>>4)<<3) + jj;
    wE0[m] = __float2half(eWhh0[col*128 + k]); return;
  }
  id -= 65536;
  if (id < 5*131072){                                // wE1,wE2,wD0,wD1,wD2: K=256, KT=8
    int seg = id >> 17, m = id & 131071;
    int jj=m&7, l=(m>>3)&63, kt=(m>>9)&7, nt=m>>12;
    int col = nt*16 + (l&15), k = kt*32 + ((l>>4)<<3) + jj;
    float v;
    if (seg==0)      v = (k<128)? eWih12[col*128+k]         : eWhh12[col*128 + (k-128)];
    else if (seg==1) v = (k<128)? eWih12[65536+col*128+k]   : eWhh12[65536 + col*128 + (k-128)];
    else if (seg==2) v = (k<128)? dWih0[col*130 + 2 + k]    : dWhh0[col*128 + (k-128)];
    else if (seg==3) v = (k<128)? dWih12[col*128+k]         : dWhh12[col*128 + (k-128)];
    else             v = (k<128)? dWih12[65536+col*128+k]   : dWhh12[65536 + col*128 + (k-128)];
    __half* dst = (seg==0)?wE1:(seg==1)?wE2:(seg==2)?wD0:(seg==3)?wD1:wD2;
    dst[m] = __float2half(v); return;
  }
  id -= 5*131072;
  if (id < 16384){                                   // wAh: attn_W[:, :H], KT=4, NT=8
    int m=id, jj=m&7, l=(m>>3)&63, kt=(m>>9)&3, nt=m>>11;
    int col = nt*16 + (l&15), k = kt*32 + ((l>>4)<<3) + jj;
    wAh[m] = __float2half(aW[col*256 + k]); return;
  }
  id -= 16384;
  if (id < 16384){                                   // wAeF: attn_W[:, H:], B-frags
    int m=id, jj=m&7, l=(m>>3)&63, kt=(m>>9)&3, nt=m>>11;
    int col = nt*16 + (l&15), k = kt*32 + ((l>>4)<<3) + jj;
    wAeF[m] = __float2half(aW[col*256 + 128 + k]); return;
  }
  id -= 16384;
  if (id < 512){ int k=id>>1, jo=id&1; wOT[id] = oW[jo*256 + k]; return; }   // [k][2] f32
  id -= 512;
  if (id < 1024){ int col=id>>1, ki=id&1; dW2[id] = dWih0[col*130 + ki]; return; } // [n][2]
}

// ---------------- encoder: 64 blocks x 512 thr, M=16 batch rows (byte-identical) ----
__global__ __launch_bounds__(512) __attribute__((amdgpu_waves_per_eu(2, 2)))
void enc_kernel(
    const float* __restrict__ x, const float* __restrict__ eb0,
    const float* __restrict__ eb12, const float* __restrict__ eWih0,
    const __half* __restrict__ wE0, const __half* __restrict__ wE1,
    const __half* __restrict__ wE2,
    __half* __restrict__ hs0, __half* __restrict__ hs1,
    __half* __restrict__ carryH, float* __restrict__ carryC)
{
  __shared__ __align__(16) __half hT[2][2048];

  const int tid = threadIdx.x, w = tid>>6, lane = tid&63;
  const int l15 = lane&15, g4 = lane>>4;
  const int j = w*16 + l15;
  const int b16 = blockIdx.x*16;
  const int K0 = ((j>>5)*64 + ((j>>3)&3)*16)*8 + (j&7);

  __half* hs0b = hs0 + (size_t)blockIdx.x*131072;
  __half* hs1b = hs1 + (size_t)blockIdx.x*131072;

  for (int layer=0; layer<3; ++layer){
    const __half* W  = (layer==0)? wE0 : (layer==1)? wE1 : wE2;
    const float* bs  = (layer==0)? eb0 : (layer==1)? eb12 : (eb12+512);
    const __half* hinb  = (layer==1)? hs0b : hs1b;     // valid for layer>0
    __half* houtb = (layer==0)? hs0b : (layer==1)? hs1b : nullptr;

    float bias[4];
#pragma unroll
    for (int g=0; g<4; ++g) bias[g] = bs[g*128 + j];
    float2 wx[4];
    if (layer==0){
#pragma unroll
      for (int g=0; g<4; ++g) wx[g] = *(const float2*)(eWih0 + (g*128+j)*2);
    }
    const f16x8* wb = (const f16x8*)W + lane;
    f16x8 Wh[16];                                    // resident W_hh slice
    if (layer==0){
#pragma unroll
      for (int g=0; g<4; ++g)
#pragma unroll
        for (int kt=0; kt<4; ++kt) Wh[g*4+kt] = wb[(size_t)((g*8+w)*4 + kt)*64];
    } else {
#pragma unroll
      for (int g=0; g<4; ++g)
#pragma unroll
        for (int kt=0; kt<4; ++kt) Wh[g*4+kt] = wb[(size_t)((g*8+w)*8 + 4 + kt)*64];
    }
    float c[4] = {0.f,0.f,0.f,0.f};
    ((u32*)hT[0])[tid] = 0u; ((u32*)hT[0])[tid+512] = 0u;
    __syncthreads();

    float2 xv[4]; f16x8 alo[4];
    if (layer==0){
#pragma unroll
      for (int q=0; q<4; ++q) xv[q] = *(const float2*)(x + ((size_t)(b16+g4*4+q)*SEQ + 0)*2);
    } else {
#pragma unroll
      for (int kt=0; kt<4; ++kt) alo[kt] = *(const f16x8*)(hinb + (kt*64+lane)*8);
    }

    int cur = 0;
    for (int t=0; t<SEQ; ++t){
      f16x8 wi[16];
      if (layer>0){                                  // stream W_ih slice (L2)
#pragma unroll
        for (int g=0; g<4; ++g)
#pragma unroll
          for (int kt=0; kt<4; ++kt) wi[g*4+kt] = wb[(size_t)((g*8+w)*8 + kt)*64];
      }
      f16x8 ah[4];
#pragma unroll
      for (int kt=0; kt<4; ++kt) ah[kt] = *(const f16x8*)(hT[cur] + (kt*64+lane)*8);
      float2 xcur[4]; f16x8 acur[4];
      if (layer==0){
#pragma unroll
        for (int q=0; q<4; ++q) xcur[q] = xv[q];
        if (t+1 < SEQ)
#pragma unroll
          for (int q=0; q<4; ++q) xv[q] = *(const float2*)(x + ((size_t)(b16+g4*4+q)*SEQ + t+1)*2);
      } else {
#pragma unroll
        for (int kt=0; kt<4; ++kt) acur[kt] = alo[kt];
        if (t+1 < SEQ)
#pragma unroll
          for (int kt=0; kt<4; ++kt) alo[kt] = *(const f16x8*)(hinb + (size_t)(t+1)*2048 + (kt*64+lane)*8);
      }
      f32x4 acc[4];
#pragma unroll
      for (int g=0; g<4; ++g) acc[g] = (f32x4){0.f,0.f,0.f,0.f};
#pragma unroll
      for (int g=0; g<4; ++g)
#pragma unroll
        for (int kt=0; kt<4; ++kt) acc[g] = MFMA(ah[kt], Wh[g*4+kt], acc[g], 0,0,0);
      if (layer>0){
#pragma unroll
        for (int g=0; g<4; ++g)
#pragma unroll
          for (int kt=0; kt<4; ++kt) acc[g] = MFMA(acur[kt], wi[g*4+kt], acc[g], 0,0,0);
      }
      // pointwise (all 16 rows)
#pragma unroll
      for (int q=0; q<4; ++q){
        float gi = acc[0][q]+bias[0], gf = acc[1][q]+bias[1],
              gg = acc[2][q]+bias[2], go = acc[3][q]+bias[3];
        if (layer==0){
          gi += xcur[q].x*wx[0].x + xcur[q].y*wx[0].y;
          gf += xcur[q].x*wx[1].x + xcur[q].y*wx[1].y;
          gg += xcur[q].x*wx[2].x + xcur[q].y*wx[2].y;
          go += xcur[q].x*wx[3].x + xcur[q].y*wx[3].y;
        }
        float cn = fmaf(sigm(gf), c[q], sigm(gi)*tanh_fast(gg));
        float hn = sigm(go)*tanh_fast(cn);
        c[q] = cn;
        __half hh = __float2half(hn);
        hT[cur^1][K0 + (g4*4+q)*8] = hh;
        if (layer < 2){
          houtb[(size_t)t*2048 + K0 + (g4*4+q)*8] = hh;
        } else {
          // encA overlay on hs0b: [d_local=g4][r4=q][sb=t>>4][ktA=j>>5][laneA][u]
          int off = g4*32768 + q*8192 + (t>>4)*2048 + (j>>5)*512
                  + ((t&15) + ((j>>3)&3)*16)*8 + (j&7);
          hs0b[off] = hh;
        }
        if (t == SEQ-1){
          int ci = (layer*1024 + b16 + g4*4 + q)*128 + j;
          carryH[ci] = hh;
          carryC[ci] = cn;
        }
      }
      __syncthreads();
      cur ^= 1;
    }
    __syncthreads();
  }
}

// ---- streamed decoder gate GEMM: depth-2 rotating queue, all indices static.
// wave w8 owns ntiles {g*8 + w8}; K=256 = [A0 | A1]. Peak live ~110 VGPRs.
#define LDQ(Q, g, kh) \
  Q[0] = wb[(size_t)((g)*64 + (kh)*4 + 0)*64]; \
  Q[1] = wb[(size_t)((g)*64 + (kh)*4 + 1)*64]; \
  Q[2] = wb[(size_t)((g)*64 + (kh)*4 + 2)*64]; \
  Q[3] = wb[(size_t)((g)*64 + (kh)*4 + 3)*64];
#define MM4(Q, A, g) \
  acc[g] = MFMA(A[0], Q[0], acc[g], 0,0,0); \
  acc[g] = MFMA(A[1], Q[1], acc[g], 0,0,0); \
  acc[g] = MFMA(A[2], Q[2], acc[g], 0,0,0); \
  acc[g] = MFMA(A[3], Q[3], acc[g], 0,0,0);

static __device__ __forceinline__ void dec_gemm(const __half* __restrict__ W,
    const __half* __restrict__ A0, const __half* __restrict__ A1,
    f32x4* acc, int lane, int w8)
{
  const f16x8* wb = (const f16x8*)W + (size_t)(w8*8)*64 + lane;
  f16x8 qA[4], qB[4], a0[4], a1[4];
  LDQ(qA, 0, 0)
  LDQ(qB, 1, 0)
#pragma unroll
  for (int kt=0; kt<4; ++kt) a0[kt] = *(const f16x8*)(A0 + (kt*64+lane)*8);
#pragma unroll
  for (int g=0; g<4; ++g) acc[g] = (f32x4){0.f,0.f,0.f,0.f};
  MM4(qA, a0, 0)  LDQ(qA, 2, 0)
  MM4(qB, a0, 1)  LDQ(qB, 3, 0)
#pragma unroll
  for (int kt=0; kt<4; ++kt) a1[kt] = *(const f16x8*)(A1 + (kt*64+lane)*8);
  MM4(qA, a0, 2)  LDQ(qA, 0, 1)
  MM4(qB, a0, 3)  LDQ(qB, 1, 1)
  MM4(qA, a1, 0)  LDQ(qA, 2, 1)
  MM4(qB, a1, 1)  LDQ(qB, 3, 1)
  MM4(qA, a1, 2)
  MM4(qB, a1, 3)
}

// ---------------- decoder: 256 blocks x 512 thr, 4 batch rows each ----------------
// 7 barriers/step (gemm+cell fused; no end-of-loop barrier).
__global__ __launch_bounds__(512)
void dec_kernel(
    const float* __restrict__ prev_y, const float* __restrict__ db0,
    const float* __restrict__ db12, const float* __restrict__ ob,
    const float* __restrict__ ab, const float* __restrict__ vW,
    const __half* __restrict__ wD0, const __half* __restrict__ wD1,
    const __half* __restrict__ wD2, const __half* __restrict__ wAh,
    const __half* __restrict__ wAeF, const float* __restrict__ wOT,
    const float* __restrict__ dW2, const __half* __restrict__ encAg,
    const __half* __restrict__ carryH, const float* __restrict__ carryC,
    float* __restrict__ dout)
{
  // hT: 0=weighted, 1=h0, 2=h1, 3=h2 (M=16 tiles, rows 0-3 real)
  __shared__ __align__(16) __half hT[4][2048];
  __shared__ float hp[4][132];
  __shared__ float scbF[256];
  __shared__ __align__(16) __half scb16h[256];
  __shared__ float po[4][2];
  __shared__ float vwl[128];
  extern __shared__ __align__(16) __half dyn[];
  __half* encBL = dyn;            // 32768 halfs: [r4][nt(8)][kt(2)][lane][8]
  __half* epL   = dyn + 32768;    // 256 x 132 halfs

  const int tid = threadIdx.x, w = tid>>6, lane = tid&63;
  const int l15 = lane&15, g4 = lane>>4;
  const int d = blockIdx.x, b4 = d*4;
  const int w8 = (w + d) & 7;                       // wave-slice decorrelation
  const int j = w8*16 + l15;                        // this wave's column slice
  const int K0 = ((j>>5)*64 + ((j>>3)&3)*16)*8 + (j&7);
  const __half* encAd = encAg + (size_t)(d>>2)*131072 + (size_t)(d&3)*32768;

  // ---- carry + constants ----
  float cD[3][4];
  if (g4 == 0){
#pragma unroll
    for (int l=0; l<3; ++l)
#pragma unroll
      for (int q=0; q<4; ++q){
        int ci = (l*1024 + b4 + q)*128 + j;
        hT[1+l][K0 + q*8] = carryH[ci];
        cD[l][q] = carryC[ci];
      }
  }
  if (tid < 8) po[tid>>1][tid&1] = prev_y[(b4 + (tid>>1))*2 + (tid&1)];
  if (tid < 128) vwl[tid] = vW[tid];

  // ---- stage encB (B-frag layout) into LDS by transpose-scatter of encA ----
#pragma unroll
  for (int it=0; it<8; ++it){
    int lin = it*512 + tid;                         // 4096 b128 chunks
    f16x8 v = *(const f16x8*)(encAd + (size_t)lin*8);
    int laneA = lin&63, ktA = (lin>>6)&3, sb = (lin>>8)&3, r4 = (lin>>10)&3;
    int s  = sb*16 + (laneA&15);
    int d0 = ktA*32 + ((laneA>>4)<<3);
    int base = r4*8192 + ((d0>>4)*2 + (s>>5))*512 + (s&7);
    int lb0  = (d0&15) + ((s>>3)&3)*16;
    f16* eb = (f16*)encBL;
#pragma unroll
    for (int u=0; u<8; ++u) eb[base + (lb0+u)*8] = v[u];
  }
  // ---- ep = enc_out @ attn_W_enc^T + ab  (MFMA, A from global encA) ----
#pragma unroll
  for (int i=0; i<2; ++i){
    int mt = w*2 + i, r4 = mt>>2, sb = mt&3;
    f16x8 a[4];
#pragma unroll
    for (int kt=0; kt<4; ++kt)
      a[kt] = *(const f16x8*)(encAd + (size_t)(((r4*4+sb)*4 + kt)*64 + lane)*8);
    const f16x8* bw = (const f16x8*)wAeF + lane;
#pragma unroll
    for (int nt=0; nt<8; ++nt){
      int col = nt*16 + l15;
      float abv = ab[col];
      f32x4 acc = {abv, abv, abv, abv};
#pragma unroll
      for (int kt=0; kt<4; ++kt) acc = MFMA(a[kt], bw[(size_t)(nt*4+kt)*64], acc, 0,0,0);
      int srow = r4*64 + sb*16 + g4*4;
#pragma unroll
      for (int q=0; q<4; ++q) epL[(srow+q)*132 + col] = __float2half(acc[q]);
    }
  }
  __syncthreads();

  // LSTM cell pointwise, rows 0-3 (g4==0 lanes); consts loaded per-call.
  auto cell = [&](float* crl, const float* bdp, const float* dwp, __half* hdst,
                  const f32x4* acc){
    float b0 = bdp[j], b1 = bdp[128+j], b2 = bdp[256+j], b3 = bdp[384+j];
    float2 w0, w1, w2, w3;
    if (dwp){
      w0 = *(const float2*)(dwp + 2*j);
      w1 = *(const float2*)(dwp + 2*(128+j));
      w2 = *(const float2*)(dwp + 2*(256+j));
      w3 = *(const float2*)(dwp + 2*(384+j));
    }
#pragma unroll
    for (int q=0; q<4; ++q){
      float gi = acc[0][q]+b0, gf = acc[1][q]+b1, gg = acc[2][q]+b2, go = acc[3][q]+b3;
      if (dwp){
        float p0 = po[q][0], p1 = po[q][1];
        gi += p0*w0.x + p1*w0.y;
        gf += p0*w1.x + p1*w1.y;
        gg += p0*w2.x + p1*w2.y;
        go += p0*w3.x + p1*w3.y;
      }
      float cn = fmaf(sigm(gf), crl[q], sigm(gi)*tanh_fast(gg));
      float hn = sigm(go)*tanh_fast(cn);
      crl[q] = cn;
      hdst[K0 + q*8] = __float2half(hn);
    }
  };

  // ---- 24 autoregressive steps, 7 barriers each ----
  int zr = 0;
  for (int t=0; t<TOUT; ++t){
    asm volatile("" : "+v"(zr));                 // opaque 0: defeats LICM hoisting
    const float*  db0t  = db0  + zr;
    const float*  db12t = db12 + zr;
    const float*  dW2t  = dW2  + zr;
    const __half* wAht  = wAh  + zr;

    { // hproj = h2 @ attn_Wh (wAh frags loaded per step, transient regs)
      f16x8 a[4], wAhR[4];
      const f16x8* wbh = (const f16x8*)wAht + lane;
#pragma unroll
      for (int kt=0; kt<4; ++kt) wAhR[kt] = wbh[(size_t)(w8*4+kt)*64];
#pragma unroll
      for (int kt=0; kt<4; ++kt) a[kt] = *(const f16x8*)(hT[3] + (kt*64+lane)*8);
      f32x4 acc = {0.f,0.f,0.f,0.f};
#pragma unroll
      for (int kt=0; kt<4; ++kt) acc = MFMA(a[kt], wAhR[kt], acc, 0,0,0);
      if (g4 == 0){
#pragma unroll
        for (int q=0; q<4; ++q) hp[q][j] = acc[q];
      }
    }
    __syncthreads();                                 // B1
    { // scores: 256 (r,s) pairs x 2 threads
      int rs = tid>>1, r = rs>>6, jh = tid&1;
      const __half* er = epL + rs*132 + jh*64;
      const float* hr = hp[r] + jh*64;
      const float* vr = vwl + jh*64;
      float sc = 0.f;
#pragma unroll
      for (int p=0; p<8; ++p){
        f16x8 e = *(const f16x8*)(er + p*8);
#pragma unroll
        for (int u=0; u<8; ++u)
          sc = fmaf(tanh_fast((float)e[u] + hr[p*8+u]), vr[p*8+u], sc);
      }
      sc += __shfl_xor(sc, 1);
      if (jh == 0) scbF[rs] = sc;
    }
    __syncthreads();                                 // B2
    if (tid < 256){ // softmax over s per row (wave = row)
      float v = scbF[tid];
      float m = v;
#pragma unroll
      for (int off=32; off; off>>=1) m = fmaxf(m, __shfl_xor(m, off));
      float e = __expf(v - m);
      float sm = e;
#pragma unroll
      for (int off=32; off; off>>=1) sm += __shfl_xor(sm, off);
      scb16h[tid] = __float2half(e * __builtin_amdgcn_rcpf(sm));
    }
    __syncthreads();                                 // B3
    { // weighted = attw @ enc_out via MFMA (A = broadcast attw row)
#pragma unroll
      for (int r=0; r<4; ++r){
        f32x4 acc = {0.f,0.f,0.f,0.f};
#pragma unroll
        for (int kt=0; kt<2; ++kt){
          f16x8 abc = *(const f16x8*)(scb16h + r*64 + kt*32 + g4*8);
          f16x8 b   = *(const f16x8*)(encBL + r*8192 + ((w8*2+kt)*64 + lane)*8);
          acc = MFMA(abc, b, acc, 0,0,0);
        }
        if (lane < 16) hT[0][K0 + r*8] = __float2half(acc[0]);
      }
    }
    __syncthreads();                                 // B4
    f32x4 acc[4];
    dec_gemm(wD0, hT[0], hT[1], acc, lane, w8);
    if (g4 == 0) cell(cD[0], db0t, dW2t, hT[1], acc);     // fused: no barrier between
    __syncthreads();                                 // B5
    dec_gemm(wD1, hT[1], hT[2], acc, lane, w8);
    if (g4 == 0) cell(cD[1], db12t, nullptr, hT[2], acc);
    __syncthreads();                                 // B6
    dec_gemm(wD2, hT[2], hT[3], acc, lane, w8);
    if (g4 == 0) cell(cD[2], db12t + 512, nullptr, hT[3], acc);
    __syncthreads();                                 // B7
    if (tid < 256){ // output head: row r = wave, from f16 frag tiles (h2 + weighted)
      int r = tid>>6, kl = tid&63;
      int k2 = kl*2;
      int sl = ((k2>>5)*64 + r + ((k2>>3)&3)*16)*8 + (k2&7);
      float2 h2f = __half22float2(*(const __half2*)(hT[3] + sl));
      float2 wwf = __half22float2(*(const __half2*)(hT[0] + sl));
      float2 a0 = *(const float2*)(wOT + k2*2);
      float2 a1 = *(const float2*)(wOT + k2*2 + 2);
      float2 b0v = *(const float2*)(wOT + (128+k2)*2);
      float2 b1v = *(const float2*)(wOT + (128+k2)*2 + 2);
      float o0 = h2f.x*a0.x + h2f.y*a1.x + wwf.x*b0v.x + wwf.y*b1v.x;
      float o1 = h2f.x*a0.y + h2f.y*a1.y + wwf.x*b0v.y + wwf.y*b1v.y;
#pragma unroll
      for (int off=32; off; off>>=1){ o0 += __shfl_xor(o0, off); o1 += __shfl_xor(o1, off); }
      if (kl == 0){
        float v0 = o0 + ob[0], v1 = o1 + ob[1];
        size_t oi = ((size_t)t*1024 + b4 + r)*2;
        dout[oi] = v0; dout[oi+1] = v1;
        po[r][0] = v0; po[r][1] = v1;
      }
    }
    // no end-of-loop barrier: outhead (waves 0-3) completes before any wave
    // can pass B1 of the next step; all cross-phase hazards separated by B1-B7.
  }
}

extern "C" void kernel_launch(void* const* d_in, const int* in_sizes, int n_in,
                              void* d_out, int out_size, void* d_ws, size_t ws_size,
                              hipStream_t stream) {
  const float* x      = (const float*)d_in[0];
  const float* prev_y = (const float*)d_in[1];
  const float* eWih0  = (const float*)d_in[2];
  const float* eWhh0  = (const float*)d_in[3];
  const float* eb0    = (const float*)d_in[4];
  const float* eWih12 = (const float*)d_in[5];
  const float* eWhh12 = (const float*)d_in[6];
  const float* eb12   = (const float*)d_in[7];
  const float* aW     = (const float*)d_in[8];
  const float* ab     = (const float*)d_in[9];
  const float* vW     = (const float*)d_in[10];
  const float* dWih0  = (const float*)d_in[11];
  const float* dWhh0  = (const float*)d_in[12];
  const float* db0    = (const float*)d_in[13];
  const float* dWih12 = (const float*)d_in[14];
  const float* dWhh12 = (const float*)d_in[15];
  const float* db12   = (const float*)d_in[16];
  const float* oW     = (const float*)d_in[17];
  const float* ob     = (const float*)d_in[18];

  __half* wE0  = (__half*)d_ws;            // 65536
  __half* wE1  = wE0 + 65536;              // 131072 each
  __half* wE2  = wE1 + 131072;
  __half* wD0  = wE2 + 131072;
  __half* wD1  = wD0 + 131072;
  __half* wD2  = wD1 + 131072;
  __half* wAh  = wD2 + 131072;             // 16384
  __half* wAeF = wAh + 16384;              // 16384
  float*  wOT  = (float*)(wAeF + 16384);   // 512 f32
  float*  dW2  = wOT + 512;                // 1024 f32
  __half* hs0  = (__half*)(dW2 + 1024);    // 64 x 131072 halfs (16 MB); encA overlays
  __half* hs1  = hs0 + (size_t)64*131072;  // 16 MB
  __half* carryH = hs1 + (size_t)64*131072;        // 393216 halfs
  float*  carryC = (float*)(carryH + 393216);      // 393216 f32

  const int prepN = 65536 + 5*131072 + 16384 + 16384 + 512 + 1024;
  prep_kernel<<<(prepN + 255)/256, 256, 0, stream>>>(
      eWih0, eWhh0, eWih12, eWhh12, aW, dWih0, dWhh0, dWih12, dWhh12, oW,
      wE0, wE1, wE2, wD0, wD1, wD2, wAh, wAeF, wOT, dW2);

  enc_kernel<<<64, 512, 0, stream>>>(
      x, eb0, eb12, eWih0, wE0, wE1, wE2, hs0, hs1, carryH, carryC);

  const int dynB = (32768 + 256*132) * 2;   // encBL + epL = 133,120 B
  hipFuncSetAttribute(reinterpret_cast<const void*>(dec_kernel),
                      hipFuncAttributeMaxDynamicSharedMemorySize, dynB);
  dec_kernel<<<256, 512, dynB, stream>>>(
      prev_y, db0, db12, ob, ab, vW, wD0, wD1, wD2, wAh, wAeF, wOT, dW2,
      hs0, carryH, carryC, (float*)d_out);
}